// Round 9
// baseline (136.950 us; speedup 1.0000x reference)
//
#include <hip/hip_runtime.h>
#include <hip/hip_bf16.h>
#include <cstdint>

// Problem constants (reference: BATCH=4096, N_VIEWS=2, T=0.07, D=128 -> N=8192)
#define NROWS 8192
#define FDIM  128
#define HALF_N 4096

typedef short bf16x8 __attribute__((ext_vector_type(8)));   // 8 bf16 = 4 VGPRs
typedef float f32x4  __attribute__((ext_vector_type(4)));

// k1 = log2(e)/T so exp((s-1)/T) = exp2(k1*s - k1)
#define K1 (1.4426950408889634f / 0.07f)

#if __has_builtin(__builtin_amdgcn_exp2f)
#define EXP2(x) __builtin_amdgcn_exp2f(x)       // raw v_exp_f32
#else
#define EXP2(x) exp2f(x)
#endif

// Fragment-packed layout of the normalized bf16 matrix:
//   frag (rb, ks) at flat bf16x8 index (rb*4+ks)*64 + lane,
//   lane = quad*16 + (r&15) holds row r = rb*16+(lane&15), k = ks*32+quad*8..+8.
// One coalesced global_load_dwordx4 per fragment. 2 MB total.

// ---------------------------------------------------------------------------
// Kernel 1: L2-normalize rows (fp32, matching ref), write fragment-packed
// bf16. Also zero-inits esum_g.
// ---------------------------------------------------------------------------
__global__ void __launch_bounds__(256) normalize_kernel(const float* __restrict__ f,
                                                        short* __restrict__ packed,
                                                        float* __restrict__ esum_g) {
    const int row  = blockIdx.x * 4 + (threadIdx.x >> 6);
    const int lane = threadIdx.x & 63;           // element k = 2*lane, 2*lane+1
    const float2 v = ((const float2*)(f + (size_t)row * FDIM))[lane];
    float ss = v.x * v.x + v.y * v.y;
    #pragma unroll
    for (int m = 1; m < 64; m <<= 1) ss += __shfl_xor(ss, m);
    const float scale = 1.0f / fmaxf(sqrtf(ss), 1e-12f);

    const int off = ((((row >> 4) * 4 + (lane >> 4)) * 64)
                     + ((lane >> 2) & 3) * 16 + (row & 15)) * 8 + 2 * (lane & 3);
    __hip_bfloat16 b0 = __float2bfloat16(v.x * scale);
    __hip_bfloat16 b1 = __float2bfloat16(v.y * scale);
    unsigned u = (unsigned)*(unsigned short*)&b0
               | ((unsigned)*(unsigned short*)&b1 << 16);
    *(unsigned*)(packed + off) = u;              // 4B-aligned (off is even)

    if (threadIdx.x < 4) esum_g[blockIdx.x * 4 + threadIdx.x] = 0.0f;
}

__device__ __forceinline__ float2 bf2_to_f2(unsigned u) {
    return make_float2(__uint_as_float(u << 16),
                       __uint_as_float(u & 0xffff0000u));
}

// ---------------------------------------------------------------------------
// Kernel 2: full-matrix fused sim+exp+rowsum, MAX A-PARK (128 rows/wave).
// Round-8 post-mortem: pipes serialize per cb (~131 cy/CU for 39 cy of MFMA);
// occupancy is irrelevant; the lever is amortization. Here each 4 KB of
// B-fragment loads feeds 32 MFMA (was 8): per-cb CU-cost ~315 cy for 4x the
// work. 2048 waves: wave = (strip of 128 rows, j of 256 cols, 16 cbs).
// Block = 4 waves, same strip, adjacent j (B-streams alias in CU L1).
// Grid 512 = 2 blocks/CU. a_reg 128 VGPR + bb 32 + acc 32 + ep 32 ~ 240.
// esum includes the diagonal term (subtracted in final via diag_g).
// Blocks 512..543: pos_i = <f_i, f_(i^4096)>, diag_i = exp((<f_i,f_i>-1)/T).
// ---------------------------------------------------------------------------
__global__ void __launch_bounds__(256, 2) sim_kernel(const short* __restrict__ pk,
                                                     float* __restrict__ esum_g,
                                                     float* __restrict__ pos_g,
                                                     float* __restrict__ diag_g) {
    if (blockIdx.x >= 512) {
        // ---- pos/diag path: one thread per row ----
        const int i  = (blockIdx.x - 512) * 256 + threadIdx.x;
        const int ip = i ^ HALF_N;
        const uint4* P = (const uint4*)pk;
        float dot = 0.f, self = 0.f;
        #pragma unroll
        for (int cc = 0; cc < 16; cc++) {        // cc = ks*4 + quad
            const uint4 a = P[((i  >> 4) * 4 + (cc >> 2)) * 64 + (cc & 3) * 16 + (i  & 15)];
            const uint4 b = P[((ip >> 4) * 4 + (cc >> 2)) * 64 + (cc & 3) * 16 + (ip & 15)];
            const unsigned au[4] = {a.x, a.y, a.z, a.w};
            const unsigned bu[4] = {b.x, b.y, b.z, b.w};
            #pragma unroll
            for (int q = 0; q < 4; q++) {
                const float2 av = bf2_to_f2(au[q]);
                const float2 bv = bf2_to_f2(bu[q]);
                dot  = __builtin_fmaf(av.x, bv.x, __builtin_fmaf(av.y, bv.y, dot));
                self = __builtin_fmaf(av.x, av.x, __builtin_fmaf(av.y, av.y, self));
            }
        }
        pos_g[i]  = dot;
        diag_g[i] = EXP2(__builtin_fmaf(self, K1, -K1));
        return;
    }

    const int tid   = threadIdx.x;
    const int w     = tid >> 6;
    const int lane  = tid & 63;
    const int quad  = lane >> 4;
    const int l16   = lane & 15;
    const int strip = blockIdx.x >> 3;                 // 0..63: rows strip*128..+128
    const int j     = (blockIdx.x & 7) * 4 + w;        // 0..31: cols j*256..+256
    const bf16x8* P = (const bf16x8*)pk;

    // A fragments for this wave's 128 rows, parked: a_reg[ks][fr] (128 VGPR)
    bf16x8 a_reg[4][8];
    #pragma unroll
    for (int fr = 0; fr < 8; fr++)
        #pragma unroll
        for (int ks = 0; ks < 4; ks++)
            a_reg[ks][fr] = P[((strip * 8 + fr) * 4 + ks) * 64 + lane];

    float ep[8][4];                              // [fr][r] row partials
    #pragma unroll
    for (int a = 0; a < 8; a++)
        #pragma unroll
        for (int b = 0; b < 4; b++) ep[a][b] = 0.0f;

    const int cb0 = j * 16;                      // 16 col-blocks of 16 cols
    bf16x8 bb[2][4];
    #pragma unroll
    for (int ks = 0; ks < 4; ks++)
        bb[0][ks] = P[(cb0 * 4 + ks) * 64 + lane];

    #pragma unroll 4
    for (int t = 0; t < 16; t++) {
        if (t < 15) {                            // prefetch next cb
            #pragma unroll
            for (int ks = 0; ks < 4; ks++)
                bb[(t + 1) & 1][ks] = P[((cb0 + t + 1) * 4 + ks) * 64 + lane];
        }

        f32x4 acc[8];
        #pragma unroll
        for (int fr = 0; fr < 8; fr++) acc[fr] = (f32x4){0.f, 0.f, 0.f, 0.f};
        #pragma unroll
        for (int ks = 0; ks < 4; ks++)
            #pragma unroll
            for (int fr = 0; fr < 8; fr++)
                acc[fr] = __builtin_amdgcn_mfma_f32_16x16x32_bf16(
                              a_reg[ks][fr], bb[t & 1][ks], acc[fr], 0, 0, 0);

        #pragma unroll
        for (int fr = 0; fr < 8; fr++)
            #pragma unroll
            for (int r = 0; r < 4; r++)
                ep[fr][r] += EXP2(__builtin_fmaf(acc[fr][r], K1, -K1));
    }

    // reduce row partials across the 16 column-lanes, commit once per wave
    #pragma unroll
    for (int fr = 0; fr < 8; fr++)
        #pragma unroll
        for (int r = 0; r < 4; r++) {
            float v = ep[fr][r];
            #pragma unroll
            for (int m = 1; m < 16; m <<= 1) v += __shfl_xor(v, m);
            if (l16 == 0)
                atomicAdd(&esum_g[strip * 128 + fr * 16 + quad * 4 + r], v);
        }
}

// ---------------------------------------------------------------------------
// Kernel 3: loss_i = ln(esum_i - diag_i) + 1/T - pos_i/T ; out = mean(loss).
// ---------------------------------------------------------------------------
__global__ void __launch_bounds__(256) final_kernel(const float* __restrict__ esum_g,
                                                    const float* __restrict__ pos_g,
                                                    const float* __restrict__ diag_g,
                                                    float* __restrict__ out) {
    const int tid = threadIdx.x;
    const float invT = 1.0f / 0.07f;
    float acc = 0.0f;
    for (int i = tid; i < NROWS; i += 256)
        acc += logf(esum_g[i] - diag_g[i]) + invT - pos_g[i] * invT;
    #pragma unroll
    for (int m = 1; m < 64; m <<= 1) acc += __shfl_xor(acc, m);
    __shared__ float ws[4];
    if ((tid & 63) == 0) ws[tid >> 6] = acc;
    __syncthreads();
    if (tid == 0) out[0] = (ws[0] + ws[1] + ws[2] + ws[3]) * (1.0f / (float)NROWS);
}

// ---------------------------------------------------------------------------
extern "C" void kernel_launch(void* const* d_in, const int* in_sizes, int n_in,
                              void* d_out, int out_size, void* d_ws, size_t ws_size,
                              hipStream_t stream) {
    const float* features = (const float*)d_in[0];
    float* out = (float*)d_out;

    char* ws = (char*)d_ws;
    short* packed = (short*)ws;                                          // 2 MB
    float* esum_g = (float*)(ws + 2097152);                              // 32 KB
    float* pos_g  = (float*)(ws + 2097152 + 32768);                      // 32 KB
    float* diag_g = (float*)(ws + 2097152 + 65536);                      // 32 KB

    normalize_kernel<<<NROWS / 4, 256, 0, stream>>>(features, packed, esum_g);

    sim_kernel<<<512 + NROWS / 256, 256, 0, stream>>>(packed, esum_g, pos_g, diag_g);

    final_kernel<<<1, 256, 0, stream>>>(esum_g, pos_g, diag_g, out);
}